// Round 11
// baseline (223.121 us; speedup 1.0000x reference)
//
#include <hip/hip_runtime.h>
#include <math.h>

#define BB 32
#define CC 256
#define CQ 32      // C/8
#define NN 1024    // H*W

typedef short bf16x8 __attribute__((ext_vector_type(8)));
typedef float f32x4  __attribute__((ext_vector_type(4)));
typedef unsigned short u16;

// fp32 -> bf16 RNE
__device__ __forceinline__ u16 f2bf(float f) {
    unsigned u = __float_as_uint(f);
    u = (u + 0x7FFFu + ((u >> 16) & 1u)) >> 16;
    return (u16)u;
}

// pack two fp32 -> two bf16 in one u32 (single VALU op)
__device__ __forceinline__ unsigned cvt_pk_bf16(float lo, float hi) {
    unsigned r;
    asm("v_cvt_pk_bf16_f32 %0, %1, %2" : "=v"(r) : "v"(lo), "v"(hi));
    return r;
}

// ---------------------------------------------------------------------------
// Device-scope grid barrier (256 blocks, all resident by construction:
// grid == CU count, lb caps VGPR at 128 so 2 blocks/CU always schedulable).
// Counter is memset-zeroed per iteration by kernel_launch (graph-safe).
// __threadfence = device-scope release/acquire: flushes/invalidates the
// per-XCD L2s around the atomic (G16 discipline).
// ---------------------------------------------------------------------------
__device__ __forceinline__ void grid_barrier(unsigned* cnt) {
    __syncthreads();                       // block's stores drained
    if (threadIdx.x == 0) {
        __threadfence();                   // release: L2 writeback
        atomicAdd(cnt, 1u);
        while (atomicAdd(cnt, 0u) < 256u)  // coherent read via atomic
            __builtin_amdgcn_s_sleep(2);
        __threadfence();                   // acquire: invalidate stale lines
    }
    __syncthreads();
}

// ---------------------------------------------------------------------------
// Fused single-launch kernel: phase W (wpack) -> barrier -> phase Q (qkv,
// r4 body verbatim, 2 halves x 2 tiles) -> barrier -> phase A (attn, r3
// body verbatim, 2 m-tile reps). 256 blocks x 512 threads.
// Rationale: residue accounting across 10 rounds shows ~50us of the
// measured time is inter-kernel launch/drain overhead, larger than any
// remaining kernel-level delta. Phase bodies are the proven-best artifacts.
// ---------------------------------------------------------------------------
struct QSmem {
    union {
        u16 xs[32][268];     // x^T tile [n][c] bf16, stride 268 (bank-spread)
        u16 osv[CC][40];     // v result [c][n]
    };
    u16 osqk[32][72];        // q|k result [n][d], d 0..31 = q, 32..63 = k
};
struct ASmem {
    u16 ps16[2][64][72];     // P dbuf, bf16, swizzled (18,432 B)
    float lsh[64];           // shared l[m]
};
union FSmem {
    QSmem q[2];              // qkv phase: one per 256-thread half (50,176 B)
    ASmem a;                 // attn phase (18,688 B)
};

__global__ __launch_bounds__(512, 4) void fused_kernel(
    const float* __restrict__ x,
    const float* __restrict__ Wq, const float* __restrict__ Wk,
    const float* __restrict__ Wv,
    const float* __restrict__ bq, const float* __restrict__ bk,
    const float* __restrict__ bv,
    const float* __restrict__ gamma_p,
    u16* __restrict__ qt, u16* __restrict__ kt, u16* __restrict__ vv,
    u16* __restrict__ wfrag, unsigned* __restrict__ cnt,
    float* __restrict__ out)
{
    __shared__ FSmem fs;
    const int bid = blockIdx.x;            // 0..255
    const int t   = threadIdx.x;           // 0..511

    // ======================= phase W: wpack =======================
    {
        const int o = bid * 512 + t;       // 131072 threads >= 81920 elems
        if (o < 81920) {
            const int j    = o & 7;
            const int lane = (o >> 3) & 63;
            const int kc   = (o >> 9) & 7;
            const int rt   = o >> 12;      // 0..19
            const int row  = rt * 16 + (lane & 15);
            const int col  = kc * 32 + (lane >> 4) * 8 + j;
            const float v = (row < 32) ? Wq[row * 256 + col]
                          : (row < 64) ? Wk[(row - 32) * 256 + col]
                                       : Wv[(row - 64) * 256 + col];
            wfrag[o] = f2bf(v);
        }
    }
    grid_barrier(&cnt[0]);

    // ======================= phase Q: qkv =========================
    {
        QSmem& S = fs.q[t >> 8];           // per-half LDS
        const int tq = t & 255;
        const int lane = tq & 63, w = tq >> 6;
        const int quad = lane >> 4, c16 = lane & 15;

#pragma unroll 1
        for (int it2 = 0; it2 < 2; ++it2) {
            const int T  = bid * 4 + (t >> 8) * 2 + it2;   // 0..1023
            const int b  = T >> 5;
            const int n0 = (T & 31) * 32;

            // ---- stage x^T bf16: 8 coalesced float4 loads, transpose-pack
            {
                const float* xb = x + (size_t)b * CC * NN + n0;
                const int n4 = (tq & 7) * 4;
                const int cr = tq >> 3;
                float4 f[8];
#pragma unroll
                for (int it = 0; it < 8; ++it)
                    f[it] = *(const float4*)(xb + (size_t)(it * 32 + cr) * NN + n4);
#pragma unroll
                for (int it = 0; it < 8; ++it) {
                    const int c = it * 32 + cr;
                    S.xs[n4 + 0][c] = f2bf(f[it].x);
                    S.xs[n4 + 1][c] = f2bf(f[it].y);
                    S.xs[n4 + 2][c] = f2bf(f[it].z);
                    S.xs[n4 + 3][c] = f2bf(f[it].w);
                }
            }
            __syncthreads();

            f32x4 acc[5][2];
#pragma unroll
            for (int i = 0; i < 5; ++i)
#pragma unroll
                for (int j = 0; j < 2; ++j) acc[i][j] = (f32x4){0.f, 0.f, 0.f, 0.f};

#pragma unroll 2
            for (int k = 0; k < 8; ++k) {
                const int c0 = k * 32;
                bf16x8 wa[5], xb[2];
#pragma unroll
                for (int rs = 0; rs < 5; ++rs)
                    wa[rs] = *(const bf16x8*)&wfrag[(size_t)(((w * 5 + rs) * 8 + k) * 64 + lane) * 8];
#pragma unroll
                for (int ns = 0; ns < 2; ++ns) {
                    const short4 a = *(const short4*)&S.xs[ns * 16 + c16][c0 + quad * 8];
                    const short4 b2 = *(const short4*)&S.xs[ns * 16 + c16][c0 + quad * 8 + 4];
                    bf16x8 v;
                    v[0] = a.x; v[1] = a.y; v[2] = a.z; v[3] = a.w;
                    v[4] = b2.x; v[5] = b2.y; v[6] = b2.z; v[7] = b2.w;
                    xb[ns] = v;
                }
#pragma unroll
                for (int rs = 0; rs < 5; ++rs)
#pragma unroll
                    for (int ns = 0; ns < 2; ++ns)
                        acc[rs][ns] = __builtin_amdgcn_mfma_f32_16x16x32_bf16(
                            wa[rs], xb[ns], acc[rs][ns], 0, 0, 0);
            }

            __syncthreads();   // xs dead; osv may alias it now

            // ---- scatter D + bias into LDS result tiles (bf16)
#pragma unroll
            for (int rs = 0; rs < 5; ++rs) {
#pragma unroll
                for (int r = 0; r < 4; ++r) {
                    const int rg = w * 80 + rs * 16 + quad * 4 + r;
                    const float bias = (rg < 32) ? bq[rg] : (rg < 64) ? bk[rg - 32] : bv[rg - 64];
#pragma unroll
                    for (int ns = 0; ns < 2; ++ns) {
                        const int n = ns * 16 + c16;
                        const u16 h = f2bf(acc[rs][ns][r] + bias);
                        if (rg < 64) S.osqk[n][rg] = h;
                        else         S.osv[rg - 64][n] = h;
                    }
                }
            }
            __syncthreads();

            // ---- coalesced global writes (standard layouts)
            {
                u16* dst = (tq >= 128) ? kt : qt;
                const int dof = (tq >= 128) ? 32 : 0;
                const int o = (tq & 127) * 8;
                const int n = o >> 5, d = o & 31;
                const bf16x8 v = *(const bf16x8*)&S.osqk[n][d + dof];
                *(bf16x8*)&dst[((size_t)b * NN + n0) * CQ + o] = v;
            }
#pragma unroll
            for (int it = 0; it < 4; ++it) {
                const int o = it * 2048 + tq * 8;
                const int c = o >> 5, n = o & 31;
                const bf16x8 v = *(const bf16x8*)&S.osv[c][n];
                *(bf16x8*)&vv[((size_t)b * CC + c) * NN + n0 + n] = v;
            }
            __syncthreads();   // osv reads done before next tile's staging
        }
    }
    grid_barrier(&cnt[1]);

    // ======================= phase A: attn (r3) ===================
    {
        const int lane = t & 63, w = t >> 6;   // w 0..7
        const int quad = lane >> 4, c16 = lane & 15;
        const int ch   = c16 >> 3;
        const int c7   = c16 & 7;
        const int qkey = (c16 >> 2) & 3;
        const int sm   = w & 3;                // S m-strip (16 rows)
        const int sh   = w >> 2;               // S n-half (32 cols)
        const int ms0  = w & 3;                // lsum ownership

        bf16x8 ones;
#pragma unroll
        for (int j = 0; j < 8; ++j) ones[j] = (short)0x3F80;

#pragma unroll 1
        for (int rep = 0; rep < 2; ++rep) {
            const int vid  = bid + rep * 256;          // 0..511
            const int xcd  = vid & 7;
            const int slot = vid >> 3;                 // 0..63
            const int b    = (xcd << 2) | (slot >> 4); // 4 batches per XCD
            const int m0   = (slot & 15) * 64;

            // Q A-frag for this wave's S m-strip
            const bf16x8 qa = *(const bf16x8*)&qt[((size_t)b * NN + m0 + sm * 16 + c16) * CQ + quad * 8];

            f32x4 accO[2][4];
            f32x4 lsum = (f32x4){0.f, 0.f, 0.f, 0.f};
#pragma unroll
            for (int cs = 0; cs < 2; ++cs)
#pragma unroll
                for (int j = 0; j < 4; ++j) accO[cs][j] = (f32x4){0.f, 0.f, 0.f, 0.f};

            const u16* vbase = vv + (size_t)b * CC * NN;
            const u16* kbase = kt + (size_t)b * NN * CQ;

            bf16x8 kb[2];
#pragma unroll
            for (int s = 0; s < 2; ++s)
                kb[s] = *(const bf16x8*)&kbase[(size_t)(sh * 32 + s * 16 + c16) * CQ + quad * 8];

            for (int step = 0; step < 16; ++step) {
                const int nbase = step * 64;
                u16* psb = &fs.a.ps16[step & 1][0][0];

                bf16x8 va[2][2];
#pragma unroll
                for (int cs = 0; cs < 2; ++cs)
#pragma unroll
                    for (int kc = 0; kc < 2; ++kc)
                        va[cs][kc] = *(const bf16x8*)&vbase[
                            (size_t)(w * 32 + cs * 16 + c16) * NN + nbase + kc * 32 + quad * 8];

                f32x4 accS[2];
#pragma unroll
                for (int s = 0; s < 2; ++s)
                    accS[s] = __builtin_amdgcn_mfma_f32_16x16x32_bf16(
                        qa, kb[s], (f32x4){0.f, 0.f, 0.f, 0.f}, 0, 0, 0);

                const int rowb = sm * 16 + quad * 4;
#pragma unroll
                for (int s = 0; s < 2; ++s) {
                    const int nb = (sh * 4 + 2 * s + ch) ^ quad;
                    u16* pw = &psb[rowb * 72 + nb * 8 + c7];
                    const float e0 = __expf(accS[s][0]);
                    const float e1 = __expf(accS[s][1]);
                    const float e2 = __expf(accS[s][2]);
                    const float e3 = __expf(accS[s][3]);
                    const unsigned p01 = cvt_pk_bf16(e0, e1);
                    const unsigned p23 = cvt_pk_bf16(e2, e3);
                    pw[0]   = (u16)p01;
                    pw[72]  = (u16)(p01 >> 16);
                    pw[144] = (u16)p23;
                    pw[216] = (u16)(p23 >> 16);
                }

                if (step < 15) {
#pragma unroll
                    for (int s = 0; s < 2; ++s)
                        kb[s] = *(const bf16x8*)&kbase[
                            (size_t)(nbase + 64 + sh * 32 + s * 16 + c16) * CQ + quad * 8];
                }

                __syncthreads();

#pragma unroll
                for (int msi = 0; msi < 4; ++msi) {
                    bf16x8 pb[2];
#pragma unroll
                    for (int kc = 0; kc < 2; ++kc)
                        pb[kc] = *(const bf16x8*)&psb[(msi * 16 + c16) * 72
                                                      + (4 * kc + (quad ^ qkey)) * 8];
                    if (msi == ms0) {
                        lsum = __builtin_amdgcn_mfma_f32_16x16x32_bf16(ones, pb[0], lsum, 0, 0, 0);
                        lsum = __builtin_amdgcn_mfma_f32_16x16x32_bf16(ones, pb[1], lsum, 0, 0, 0);
                    }
#pragma unroll
                    for (int cs = 0; cs < 2; ++cs)
#pragma unroll
                        for (int kc = 0; kc < 2; ++kc)
                            accO[cs][msi] = __builtin_amdgcn_mfma_f32_16x16x32_bf16(
                                va[cs][kc], pb[kc], accO[cs][msi], 0, 0, 0);
                }
            }

            if (sh == 0 && quad == 0) fs.a.lsh[ms0 * 16 + c16] = lsum[0];
            __syncthreads();

            const float gamma = gamma_p[0];
#pragma unroll
            for (int ms = 0; ms < 4; ++ms) {
                const float inv = gamma / fs.a.lsh[ms * 16 + c16];
                const int m = m0 + ms * 16 + c16;
#pragma unroll
                for (int cs = 0; cs < 2; ++cs) {
                    const int cbase = w * 32 + cs * 16 + quad * 4;
#pragma unroll
                    for (int r = 0; r < 4; ++r) {
                        const size_t idx = ((size_t)b * CC + cbase + r) * NN + m;
                        out[idx] = accO[cs][ms][r] * inv + x[idx];
                    }
                }
            }
            __syncthreads();   // lsh/ps16 safe for next rep
        }
    }
}

// ---------------------------------------------------------------------------
extern "C" void kernel_launch(void* const* d_in, const int* in_sizes, int n_in,
                              void* d_out, int out_size, void* d_ws, size_t ws_size,
                              hipStream_t stream)
{
    const float* x  = (const float*)d_in[0];
    const float* Wq = (const float*)d_in[1];
    const float* bq = (const float*)d_in[2];
    const float* Wk = (const float*)d_in[3];
    const float* bk = (const float*)d_in[4];
    const float* Wv = (const float*)d_in[5];
    const float* bv = (const float*)d_in[6];
    const float* gm = (const float*)d_in[7];
    float* out = (float*)d_out;

    // workspace (bf16): qt 2MB | kt 2MB | vv 16MB | wfrag 160KB | counters
    u16* qt    = (u16*)d_ws;
    u16* kt    = qt + (size_t)BB * NN * CQ;
    u16* vv    = kt + (size_t)BB * NN * CQ;
    u16* wfrag = vv + (size_t)BB * CC * NN;
    unsigned* cnt = (unsigned*)(wfrag + 81920);

    hipMemsetAsync(cnt, 0, 2 * sizeof(unsigned), stream);
    fused_kernel<<<256, 512, 0, stream>>>(x, Wq, Wk, Wv, bq, bk, bv, gm,
                                          qt, kt, vv, wfrag, cnt, out);
}